// Round 1
// baseline (5295.218 us; speedup 1.0000x reference)
//
#include <hip/hip_runtime.h>

#define LEAKY(v) ((v) >= 0.f ? (v) : 0.01f * (v))

// Generic direct 3x3 conv, NCHW, W=256, width-pad 1, height-pad PH (0 or 1).
// grid: (1, Hout, 16 * NZ)  block: 256 (one thread per output column)
// blockIdx.z = z*16 + cout_group; each thread computes 4 couts for its column.
// z selects tower (input offset z*inZS, weights w1/b1 when z==1, output offset z*outZS).
__global__ void convk(const float* __restrict__ in, int inChS, int inRow0, int Hin, int inZS,
                      const float* __restrict__ w0, const float* __restrict__ b0,
                      const float* __restrict__ w1, const float* __restrict__ b1,
                      float* __restrict__ out, int outZS, int Hout, int CIN, int PH)
{
    const int wcol = threadIdx.x;      // 0..255
    const int h    = blockIdx.y;       // output row
    const int cg   = blockIdx.z & 15;  // cout group (4 couts each)
    const int z    = blockIdx.z >> 4;  // tower
    const float* W  = z ? w1 : w0;
    const float* Bv = z ? b1 : b0;
    const float* inp = in + (size_t)z * inZS;
    float* o = out + (size_t)z * outZS;
    const int coutBase = cg * 4;
    const int wstride = CIN * 9;       // weight stride per cout

    float a0 = Bv[coutBase + 0];
    float a1 = Bv[coutBase + 1];
    float a2 = Bv[coutBase + 2];
    float a3 = Bv[coutBase + 3];

    for (int cin = 0; cin < CIN; ++cin) {
        const float* ib = inp + cin * inChS + (inRow0 + h - PH) * 256;
        const float* wb = W + coutBase * wstride + cin * 9;
        #pragma unroll
        for (int kh = 0; kh < 3; ++kh) {
            const int r = h + kh - PH;   // slice-relative input row
            float vm = 0.f, v0 = 0.f, vp = 0.f;
            if (PH == 0 || (r >= 0 && r < Hin)) {
                const float* row = ib + kh * 256;
                vm = (wcol > 0)   ? row[wcol - 1] : 0.f;
                v0 = row[wcol];
                vp = (wcol < 255) ? row[wcol + 1] : 0.f;
            }
            const float* wk = wb + kh * 3;
            a0 += vm * wk[0]              + v0 * wk[1]              + vp * wk[2];
            a1 += vm * wk[wstride + 0]    + v0 * wk[wstride + 1]    + vp * wk[wstride + 2];
            a2 += vm * wk[2 * wstride + 0] + v0 * wk[2 * wstride + 1] + vp * wk[2 * wstride + 2];
            a3 += vm * wk[3 * wstride + 0] + v0 * wk[3 * wstride + 1] + vp * wk[3 * wstride + 2];
        }
    }

    const int ohw = Hout * 256;
    o[(coutBase + 0) * ohw + h * 256 + wcol] = LEAKY(a0);
    o[(coutBase + 1) * ohw + h * 256 + wcol] = LEAKY(a1);
    o[(coutBase + 2) * ohw + h * 256 + wcol] = LEAKY(a2);
    o[(coutBase + 3) * ohw + h * 256 + wcol] = LEAKY(a3);
}

// Per-pixel 8x8 @ 8x8: pr[8i+k] = sum_j e[8i+j] * s[8j+k]
// tw holds both tower outputs: z0 (s, x-weights) then z1 (e), each 64x9x256.
__global__ void mm88(const float* __restrict__ tw, float* __restrict__ p0)
{
    const int idx = blockIdx.x * 256 + threadIdx.x;  // pixel in 9*256
    if (idx >= 9 * 256) return;
    const float* s = tw;
    const float* e = tw + 64 * 9 * 256;
    float sv[64], ev[64];
    #pragma unroll
    for (int c = 0; c < 64; ++c) {
        sv[c] = s[c * 9 * 256 + idx];
        ev[c] = e[c * 9 * 256 + idx];
    }
    #pragma unroll
    for (int i = 0; i < 8; ++i) {
        #pragma unroll
        for (int k = 0; k < 8; ++k) {
            float acc = 0.f;
            #pragma unroll
            for (int j = 0; j < 8; ++j) acc += ev[i * 8 + j] * sv[j * 8 + k];
            p0[(i * 8 + k) * 9 * 256 + idx] = acc;  // no bias, no leaky
        }
    }
}

// conv9: 64->3, ph=1 on H=1 input (only kh=1 taps live), leaky, then
// pred row store + ebuf[i+15] = x[i+15] - pr.
__global__ void conv9up(const float* __restrict__ pin, const float* __restrict__ w9,
                        const float* __restrict__ b9, const float* __restrict__ x,
                        float* __restrict__ ebuf, float* __restrict__ preds, int i)
{
    const int wcol = threadIdx.x;  // 0..255
    float acc0 = b9[0], acc1 = b9[1], acc2 = b9[2];
    for (int cin = 0; cin < 64; ++cin) {
        const float* row = pin + cin * 256;
        float vm = (wcol > 0)   ? row[wcol - 1] : 0.f;
        float v0 = row[wcol];
        float vp = (wcol < 255) ? row[wcol + 1] : 0.f;
        const float* wk0 = w9 + (0 * 64 + cin) * 9 + 3;  // kh=1
        const float* wk1 = w9 + (1 * 64 + cin) * 9 + 3;
        const float* wk2 = w9 + (2 * 64 + cin) * 9 + 3;
        acc0 += vm * wk0[0] + v0 * wk0[1] + vp * wk0[2];
        acc1 += vm * wk1[0] + v0 * wk1[1] + vp * wk1[2];
        acc2 += vm * wk2[0] + v0 * wk2[1] + vp * wk2[2];
    }
    float v;
    v = LEAKY(acc0);
    preds[i * 768 + 0 * 256 + wcol] = v;
    ebuf[0 * 31 * 256 + (15 + i) * 256 + wcol] = x[0 * 31 * 256 + (15 + i) * 256 + wcol] - v;
    v = LEAKY(acc1);
    preds[i * 768 + 1 * 256 + wcol] = v;
    ebuf[1 * 31 * 256 + (15 + i) * 256 + wcol] = x[1 * 31 * 256 + (15 + i) * 256 + wcol] - v;
    v = LEAKY(acc2);
    preds[i * 768 + 2 * 256 + wcol] = v;
    ebuf[2 * 31 * 256 + (15 + i) * 256 + wcol] = x[2 * 31 * 256 + (15 + i) * 256 + wcol] - v;
}

// Assemble d_out: [pred (3,16,256) | truth (3,16,256)]
__global__ void finalize(const float* __restrict__ preds, const float* __restrict__ ebuf,
                         float* __restrict__ o)
{
    const int idx = blockIdx.x * 256 + threadIdx.x;
    if (idx >= 24576) return;
    if (idx < 12288) {
        const int c = idx >> 12;
        const int t = (idx >> 8) & 15;
        const int w = idx & 255;
        o[idx] = preds[t * 768 + c * 256 + w];
    } else {
        const int j = idx - 12288;
        const int c = j >> 12;
        const int t = (j >> 8) & 15;
        const int w = j & 255;
        o[idx] = ebuf[c * 31 * 256 + (15 + t) * 256 + w];
    }
}

extern "C" void kernel_launch(void* const* d_in, const int* in_sizes, int n_in,
                              void* d_out, int out_size, void* d_ws, size_t ws_size,
                              hipStream_t stream)
{
    const float* x   = (const float*)d_in[0];
    const float* w1x = (const float*)d_in[1];  const float* b1x = (const float*)d_in[2];
    const float* w2x = (const float*)d_in[3];  const float* b2x = (const float*)d_in[4];
    const float* w3x = (const float*)d_in[5];  const float* b3x = (const float*)d_in[6];
    const float* w4x = (const float*)d_in[7];  const float* b4x = (const float*)d_in[8];
    const float* w1e = (const float*)d_in[9];  const float* b1e = (const float*)d_in[10];
    const float* w2e = (const float*)d_in[11]; const float* b2e = (const float*)d_in[12];
    const float* w3e = (const float*)d_in[13]; const float* b3e = (const float*)d_in[14];
    const float* w4e = (const float*)d_in[15]; const float* b4e = (const float*)d_in[16];
    const float* w5  = (const float*)d_in[17]; const float* b5  = (const float*)d_in[18];
    const float* w6  = (const float*)d_in[19]; const float* b6  = (const float*)d_in[20];
    const float* w7  = (const float*)d_in[21]; const float* b7  = (const float*)d_in[22];
    const float* w8  = (const float*)d_in[23]; const float* b8  = (const float*)d_in[24];
    const float* w9  = (const float*)d_in[25]; const float* b9  = (const float*)d_in[26];

    float* ws    = (float*)d_ws;
    float* ebuf  = ws;                   // 3*31*256      = 23808
    float* tA    = ebuf + 23808;         // 2*64*15*256   = 491520
    float* tB    = tA + 491520;          // 2*64*15*256   = 491520
    float* p0    = tB + 491520;          // 64*9*256      = 147456
    float* p1    = p0 + 147456;          // 64*9*256      = 147456
    float* preds = p1 + 147456;          // 16*3*256      = 12288

    hipMemcpyAsync(ebuf, x, 23808 * sizeof(float), hipMemcpyDeviceToDevice, stream);

    for (int i = 0; i < 16; ++i) {
        // towers (dual: z=0 -> x-weights (s), z=1 -> e-weights)
        convk<<<dim3(1, 15, 32), 256, 0, stream>>>(ebuf, 31 * 256, i, 15, 0,
                                                   w1x, b1x, w1e, b1e,
                                                   tA, 64 * 15 * 256, 15, 3, 1);
        convk<<<dim3(1, 13, 32), 256, 0, stream>>>(tA, 15 * 256, 0, 15, 64 * 15 * 256,
                                                   w2x, b2x, w2e, b2e,
                                                   tB, 64 * 13 * 256, 13, 64, 0);
        convk<<<dim3(1, 11, 32), 256, 0, stream>>>(tB, 13 * 256, 0, 13, 64 * 13 * 256,
                                                   w3x, b3x, w3e, b3e,
                                                   tA, 64 * 11 * 256, 11, 64, 0);
        convk<<<dim3(1, 9, 32), 256, 0, stream>>>(tA, 11 * 256, 0, 11, 64 * 11 * 256,
                                                  w4x, b4x, w4e, b4e,
                                                  tB, 64 * 9 * 256, 9, 64, 0);
        // per-pixel 8x8 matmul (s = z0, e = z1)
        mm88<<<9, 256, 0, stream>>>(tB, p0);
        // tail convs
        convk<<<dim3(1, 7, 16), 256, 0, stream>>>(p0, 9 * 256, 0, 9, 0,
                                                  w5, b5, w5, b5, p1, 0, 7, 64, 0);
        convk<<<dim3(1, 5, 16), 256, 0, stream>>>(p1, 7 * 256, 0, 7, 0,
                                                  w6, b6, w6, b6, p0, 0, 5, 64, 0);
        convk<<<dim3(1, 3, 16), 256, 0, stream>>>(p0, 5 * 256, 0, 5, 0,
                                                  w7, b7, w7, b7, p1, 0, 3, 64, 0);
        convk<<<dim3(1, 1, 16), 256, 0, stream>>>(p1, 3 * 256, 0, 3, 0,
                                                  w8, b8, w8, b8, p0, 0, 1, 64, 0);
        // conv9 + recurrence update
        conv9up<<<1, 256, 0, stream>>>(p0, w9, b9, x, ebuf, preds, i);
    }

    finalize<<<96, 256, 0, stream>>>(preds, ebuf, (float*)d_out);
}